// Round 12
// baseline (412.418 us; speedup 1.0000x reference)
//
#include <hip/hip_runtime.h>
#include <hip/hip_fp16.h>
#include <math.h>

#define NS   1024
#define TIN  4096
#define T1   2048
#define T2   1024
#define TW   64
#define NG   8
#define DD   128

typedef __attribute__((ext_vector_type(8))) _Float16 f16x8;
typedef __attribute__((ext_vector_type(4))) float    f32x4;

// tanh-form gelu, exp folded to exp2 (|dev from exact| ~3e-4)
__device__ __forceinline__ float gelu_fast(float x) {
  float t = x * x;
  float p = fmaf(0.044715f, t, 1.0f);
  float u = 2.3022038f * x * p;              // 2*sqrt(2/pi)*log2(e)
  float e = exp2f(u);
  float r = __builtin_amdgcn_rcpf(e + 1.0f);
  return fmaf(-x, r, x);                      // x * e/(e+1)
}

// ---------------- Kernel A: conv1 stats per n via 9x9 Gram matrix ---------
__global__ __launch_bounds__(64) void k_stats1(
    const float* __restrict__ x, const float* __restrict__ w1,
    float* __restrict__ stats1) {
  int n = blockIdx.x;
  __shared__ float xw[4112];
  const float* xr = x + (size_t)n * TIN;
  for (int i = threadIdx.x; i < 4112; i += 64) {
    int xi = i - 4;
    xw[i] = (xi >= 0 && xi < TIN) ? xr[xi] : 0.f;
  }
  __syncthreads();
  float C[45], S[9];
#pragma unroll
  for (int c = 0; c < 45; c++) C[c] = 0.f;
#pragma unroll
  for (int i = 0; i < 9; i++) S[i] = 0.f;
  int l = threadIdx.x;
  for (int j = 0; j < 32; j++) {
    int t = l + 64 * j;
    float w[9];
#pragma unroll
    for (int i = 0; i < 9; i++) w[i] = xw[2 * t + i];
#pragma unroll
    for (int i = 0; i < 9; i++) S[i] += w[i];
    int c = 0;
#pragma unroll
    for (int i = 0; i < 9; i++)
#pragma unroll
      for (int jj = i; jj < 9; jj++) { C[c] = fmaf(w[i], w[jj], C[c]); c++; }
  }
#pragma unroll
  for (int off = 1; off < 64; off <<= 1) {
#pragma unroll
    for (int i = 0; i < 9; i++) S[i] += __shfl_xor(S[i], off, 64);
#pragma unroll
    for (int c = 0; c < 45; c++) C[c] += __shfl_xor(C[c], off, 64);
  }
  float wv[9];
#pragma unroll
  for (int i = 0; i < 9; i++) wv[i] = w1[l * 9 + i];
  float sm = 0.f, sq = 0.f;
  {
    int c = 0;
#pragma unroll
    for (int i = 0; i < 9; i++) {
      sm = fmaf(wv[i], S[i], sm);
#pragma unroll
      for (int jj = i; jj < 9; jj++) {
        float f = (jj == i) ? wv[i] * wv[jj] : 2.f * wv[i] * wv[jj];
        sq = fmaf(f, C[c], sq); c++;
      }
    }
  }
#pragma unroll
  for (int off = 1; off < 8; off <<= 1) {
    sm += __shfl_xor(sm, off, 64);
    sq += __shfl_xor(sq, off, 64);
  }
  if ((l & 7) == 0) {
    float m = sm * (1.f / 16384.f);
    float v = sq * (1.f / 16384.f) - m * m;
    stats1[(n * NG + (l >> 3)) * 2 + 0] = m;
    stats1[(n * NG + (l >> 3)) * 2 + 1] = rsqrtf(v + 1e-5f);
  }
}

// ---------------- Kernel P: weight prep -> f16, w2 [kk][co][ci] -----------
__global__ __launch_bounds__(256) void k_prep(
    const float* __restrict__ w2, const float* __restrict__ w1,
    _Float16* __restrict__ w2tf, _Float16* __restrict__ w1h) {
  int idx = blockIdx.x * 256 + threadIdx.x;
  if (idx < 7 * 64 * 64) {
    int kk = idx >> 12;
    int r = idx & 4095;
    int co = r >> 6, ci = r & 63;
    w2tf[idx] = (_Float16)w2[(co * 64 + ci) * 7 + kk];
  } else {
    int r = idx - 28672;
    if (r < 64 * 32) {
      int ci = r >> 5, k = r & 31;
      w1h[r] = (k < 9) ? (_Float16)w1[ci * 9 + k] : (_Float16)0.f;
    }
  }
}

// ---------------- Kernel B: conv1(MFMA)+GN1+gelu -> conv2(MFMA) -> y2 -----
// R5 structure; phase B waves split 2x2 (32t x 32co) to halve A-LDS reads.
__global__ __launch_bounds__(256, 6) void k_conv(
    const float* __restrict__ x, const _Float16* __restrict__ w1h,
    const float* __restrict__ g1, const float* __restrict__ b1,
    const float* __restrict__ stats1, const _Float16* __restrict__ w2tf,
    __half* __restrict__ y2, float* __restrict__ stats2) {
  constexpr int ROWS = 144, HS = 72;
  __shared__ _Float16 h1s[ROWS * HS];         // 20736 B; reused as tr[64][72]
  __shared__ _Float16 xh[320];
  __shared__ float scs[TW], bss[TW];

  const int tid = threadIdx.x;
  const int n = blockIdx.x >> 4;
  const int tile = blockIdx.x & 15;
  const int t0 = tile << 6;
  const bool chk = (tile == 0) || (tile == 15);

  const float* xr = x + (size_t)n * TIN;
  for (int i = tid; i < 320; i += 256) {
    int xi = 4 * t0 - 10 + i;
    xh[i] = (i < 278 && xi >= 0 && xi < TIN) ? (_Float16)xr[xi] : (_Float16)0.f;
  }
  if (tid < TW) {
    int ci = tid, g = ci >> 3;
    float m = stats1[(n * NG + g) * 2 + 0];
    float is = stats1[(n * NG + g) * 2 + 1];
    float s = is * g1[ci];
    scs[ci] = s;
    bss[ci] = b1[ci] - m * s;
  }
  __syncthreads();

  const int lane = tid & 63;
  const int wv = tid >> 6;
  const int m = lane & 15;
  const int q = lane >> 4;

  // ---- phase A: conv1 via f16 MFMA (K padded 9->32), GN1+gelu, store f16 --
  {
    f16x8 w1f[4];
#pragma unroll
    for (int nt = 0; nt < 4; nt++)
      w1f[nt] = *(const f16x8*)&w1h[(nt * 16 + m) * 32 + 8 * q];
    float sc4[4], bs4[4];
#pragma unroll
    for (int nt = 0; nt < 4; nt++) {
      sc4[nt] = scs[nt * 16 + m];
      bs4[nt] = bss[nt * 16 + m];
    }
    for (int mt = wv; mt < 9; mt += 4) {
      int r0 = mt * 16;
      int xi0 = 2 * (r0 + m) + 8 * q;
      uint4 uu;
      uu.x = *(const unsigned*)&xh[xi0 + 0];
      uu.y = *(const unsigned*)&xh[xi0 + 2];
      uu.z = *(const unsigned*)&xh[xi0 + 4];
      uu.w = *(const unsigned*)&xh[xi0 + 6];
      f16x8 af = __builtin_bit_cast(f16x8, uu);
      int rowb = r0 + 4 * q;
#pragma unroll
      for (int nt = 0; nt < 4; nt++) {
        f32x4 d = __builtin_amdgcn_mfma_f32_16x16x32_f16(
            af, w1f[nt], (f32x4){0.f, 0.f, 0.f, 0.f}, 0, 0, 0);
#pragma unroll
        for (int r = 0; r < 4; r++) {
          float v = gelu_fast(fmaf(d[r], sc4[nt], bs4[nt]));
          if (chk) {
            int tp = 2 * t0 - 3 + rowb + r;
            if ((unsigned)tp >= (unsigned)T1) v = 0.f;
          }
          h1s[(rowb + r) * HS + nt * 16 + m] = (_Float16)v;
        }
      }
    }
  }
  __syncthreads();

  // ---- phase B: conv2 f16 MFMA. wave = 32 t x 32 co (2x2 tiles) ----
  const int tpart = wv & 1;
  const int npart = wv >> 1;
  f32x4 acc[2][2];
#pragma unroll
  for (int mt = 0; mt < 2; mt++)
#pragma unroll
    for (int nt = 0; nt < 2; nt++) acc[mt][nt] = (f32x4){0.f, 0.f, 0.f, 0.f};

  for (int kk = 0; kk < 7; kk++) {
    f16x8 bfr[2][2];
#pragma unroll
    for (int nt = 0; nt < 2; nt++) {
      int co = npart * 32 + nt * 16 + m;
#pragma unroll
      for (int ks = 0; ks < 2; ks++)
        bfr[nt][ks] = *(const f16x8*)&w2tf[(kk * 64 + co) * 64 + 32 * ks + 8 * q];
    }
#pragma unroll
    for (int mt = 0; mt < 2; mt++) {
      int tl = 2 * (tpart * 32 + mt * 16 + m) + kk;
      f16x8 a0 = *(const f16x8*)&h1s[tl * HS + 8 * q];
      f16x8 a1 = *(const f16x8*)&h1s[tl * HS + 32 + 8 * q];
#pragma unroll
      for (int nt = 0; nt < 2; nt++) {
        acc[mt][nt] = __builtin_amdgcn_mfma_f32_16x16x32_f16(a0, bfr[nt][0], acc[mt][nt], 0, 0, 0);
        acc[mt][nt] = __builtin_amdgcn_mfma_f32_16x16x32_f16(a1, bfr[nt][1], acc[mt][nt], 0, 0, 0);
      }
    }
  }

  // ---- epilogue: GN2 stats + transpose via LDS + coalesced y2 store ----
  float sum[2] = {0.f, 0.f}, ssq[2] = {0.f, 0.f};
#pragma unroll
  for (int mt = 0; mt < 2; mt++)
#pragma unroll
    for (int nt = 0; nt < 2; nt++)
#pragma unroll
      for (int r = 0; r < 4; r++) {
        float v = acc[mt][nt][r];
        sum[nt] += v; ssq[nt] += v * v;
      }
#pragma unroll
  for (int nt = 0; nt < 2; nt++) {
    sum[nt] += __shfl_xor(sum[nt], 16, 64); ssq[nt] += __shfl_xor(ssq[nt], 16, 64);
    sum[nt] += __shfl_xor(sum[nt], 32, 64); ssq[nt] += __shfl_xor(ssq[nt], 32, 64);
    sum[nt] += __shfl_xor(sum[nt], 1, 64);  ssq[nt] += __shfl_xor(ssq[nt], 1, 64);
    sum[nt] += __shfl_xor(sum[nt], 2, 64);  ssq[nt] += __shfl_xor(ssq[nt], 2, 64);
    sum[nt] += __shfl_xor(sum[nt], 4, 64);  ssq[nt] += __shfl_xor(ssq[nt], 4, 64);
  }
  if (lane == 0 || lane == 8) {
#pragma unroll
    for (int nt = 0; nt < 2; nt++) {
      int g = npart * 4 + nt * 2 + (lane >> 3);
      atomicAdd(&stats2[(n * NG + g) * 2 + 0], sum[nt]);
      atomicAdd(&stats2[(n * NG + g) * 2 + 1], ssq[nt]);
    }
  }

  __syncthreads();                      // all h1s reads done; reuse as tr
  __half* tr = (__half*)h1s;            // [64 t][72] fp16
#pragma unroll
  for (int mt = 0; mt < 2; mt++)
#pragma unroll
    for (int nt = 0; nt < 2; nt++)
#pragma unroll
      for (int r = 0; r < 4; r++) {
        int t = tpart * 32 + mt * 16 + q * 4 + r;
        tr[t * HS + npart * 32 + nt * 16 + m] = __float2half(acc[mt][nt][r]);
      }
  __syncthreads();
  for (int idx = tid; idx < 512; idx += 256) {
    int t = idx >> 3, c8 = (idx & 7) * 8;
    float4 v = *(float4*)&tr[t * HS + c8];
    *(float4*)&y2[((size_t)(n * 1024) + t0 + t) * 64 + c8] = v;
  }
}

// ---------------- Kernel C: GN2 + gelu + time-sum -> hbar (atomic) --------
__global__ __launch_bounds__(256) void k_gn2mean(
    const __half* __restrict__ y2, const float* __restrict__ stats2,
    const float* __restrict__ g2, const float* __restrict__ b2,
    float* __restrict__ hbar) {
  int n = blockIdx.x >> 2;
  int tq = blockIdx.x & 3;
  int coct = threadIdx.x & 7;
  int tsl = threadIdx.x >> 3;
  int co0 = coct * 8;
  float mn = stats2[(n * NG + coct) * 2 + 0] * (1.f / 8192.f);
  float e2 = stats2[(n * NG + coct) * 2 + 1] * (1.f / 8192.f);
  float istd = rsqrtf(e2 - mn * mn + 1e-5f);
  float sca[8], sh[8];
#pragma unroll
  for (int j = 0; j < 8; j++) {
    sca[j] = istd * g2[co0 + j];
    sh[j] = b2[co0 + j] - mn * sca[j];
  }
  const __half* base = y2 + (size_t)n * 65536 + tq * (256 * 64);
  float4 raw[8];
#pragma unroll
  for (int i = 0; i < 8; i++)
    raw[i] = *(const float4*)&base[(tsl + 32 * i) * 64 + co0];
  float a[8];
#pragma unroll
  for (int j = 0; j < 8; j++) a[j] = 0.f;
#pragma unroll
  for (int i = 0; i < 8; i++) {
    __half2 hh[4];
    *(float4*)hh = raw[i];
#pragma unroll
    for (int p = 0; p < 4; p++) {
      float2 f = __half22float2(hh[p]);
      a[2 * p]     += gelu_fast(fmaf(f.x, sca[2 * p], sh[2 * p]));
      a[2 * p + 1] += gelu_fast(fmaf(f.y, sca[2 * p + 1], sh[2 * p + 1]));
    }
  }
  __shared__ float red[32][64];
  *(float4*)&red[tsl][co0] = *(float4*)&a[0];
  *(float4*)&red[tsl][co0 + 4] = *(float4*)&a[4];
  __syncthreads();
  if (threadIdx.x < 64) {
    float s = 0.f;
#pragma unroll 8
    for (int r = 0; r < 32; r++) s += red[r][threadIdx.x];
    atomicAdd(&hbar[n * 64 + threadIdx.x], s);
  }
}

// ---------------- Kernel D: proj + GCN layers + LN + node mean ------------
__global__ __launch_bounds__(256) void k_head(
    const float* __restrict__ hbar,
    const float* __restrict__ pw, const float* __restrict__ pb,
    const float* __restrict__ A,
    const float* __restrict__ l1w, const float* __restrict__ l1g, const float* __restrict__ l1b,
    const float* __restrict__ l2w, const float* __restrict__ l2g, const float* __restrict__ l2b,
    const float* __restrict__ og, const float* __restrict__ ob,
    float* __restrict__ out) {
  int b = blockIdx.x;
  __shared__ float h4[4][TW];
  __shared__ float H[4][DD];
  __shared__ float Hm[4][DD];
  __shared__ float Xs[4][DD];
  __shared__ float At[16], Ah[16], dinv[4];
  {
    int i = threadIdx.x;
    int c = i >> 6, k = i & 63;
    h4[c][k] = hbar[(b * 4 + c) * TW + k] * (1.f / 1024.f);
  }
  if (threadIdx.x < 16)
    At[threadIdx.x] = A[threadIdx.x] + ((threadIdx.x % 5) == 0 ? 1.f : 0.f);
  __syncthreads();
  if (threadIdx.x < 4) {
    float dg = At[threadIdx.x * 4] + At[threadIdx.x * 4 + 1] +
               At[threadIdx.x * 4 + 2] + At[threadIdx.x * 4 + 3];
    dinv[threadIdx.x] = rsqrtf(dg + 1e-6f);
  }
  for (int idx = threadIdx.x; idx < 512; idx += 256) {
    int c = idx >> 7, d = idx & 127;
    float acc = pb[d];
    const float* wrow = pw + d * TW;
#pragma unroll 8
    for (int k = 0; k < TW; k++) acc += h4[c][k] * wrow[k];
    H[c][d] = acc;
  }
  __syncthreads();
  if (threadIdx.x < 16)
    Ah[threadIdx.x] = dinv[threadIdx.x >> 2] * At[threadIdx.x] * dinv[threadIdx.x & 3];
  __syncthreads();
  for (int L = 0; L < 2; L++) {
    const float* lw = L ? l2w : l1w;
    const float* lg = L ? l2g : l1g;
    const float* lb = L ? l2b : l1b;
    for (int idx = threadIdx.x; idx < 512; idx += 256) {
      int nn = idx >> 7, d = idx & 127;
      Hm[nn][d] = Ah[nn * 4 + 0] * H[0][d] + Ah[nn * 4 + 1] * H[1][d] +
                  Ah[nn * 4 + 2] * H[2][d] + Ah[nn * 4 + 3] * H[3][d];
    }
    __syncthreads();
    for (int idx = threadIdx.x; idx < 512; idx += 256) {
      int nn = idx >> 7, d = idx & 127;
      float acc = 0.f;
      const float* wrow = lw + d * DD;
#pragma unroll 8
      for (int k = 0; k < DD; k++) acc += Hm[nn][k] * wrow[k];
      Xs[nn][d] = acc;
    }
    __syncthreads();
    {
      int w = threadIdx.x >> 6, lane = threadIdx.x & 63;
      float v0 = Xs[w][lane], v1 = Xs[w][lane + 64];
      float s = v0 + v1, qq = v0 * v0 + v1 * v1;
#pragma unroll
      for (int off = 1; off < 64; off <<= 1) {
        s += __shfl_xor(s, off, 64);
        qq += __shfl_xor(qq, off, 64);
      }
      float mm = s * (1.f / 128.f);
      float istd = rsqrtf(qq * (1.f / 128.f) - mm * mm + 1e-5f);
      H[w][lane]      = gelu_fast((v0 - mm) * istd * lg[lane] + lb[lane]);
      H[w][lane + 64] = gelu_fast((v1 - mm) * istd * lg[lane + 64] + lb[lane + 64]);
    }
    __syncthreads();
  }
  {
    int w = threadIdx.x >> 6, lane = threadIdx.x & 63;
    float v0 = H[w][lane], v1 = H[w][lane + 64];
    float s = v0 + v1, qq = v0 * v0 + v1 * v1;
#pragma unroll
    for (int off = 1; off < 64; off <<= 1) {
      s += __shfl_xor(s, off, 64);
      qq += __shfl_xor(qq, off, 64);
    }
    float mm = s * (1.f / 128.f);
    float istd = rsqrtf(qq * (1.f / 128.f) - mm * mm + 1e-5f);
    Xs[w][lane]      = (v0 - mm) * istd * og[lane] + ob[lane];
    Xs[w][lane + 64] = (v1 - mm) * istd * og[lane + 64] + ob[lane + 64];
  }
  __syncthreads();
  if (threadIdx.x < DD) {
    int d = threadIdx.x;
    out[b * DD + d] = 0.25f * (Xs[0][d] + Xs[1][d] + Xs[2][d] + Xs[3][d]);
  }
}

extern "C" void kernel_launch(void* const* d_in, const int* in_sizes, int n_in,
                              void* d_out, int out_size, void* d_ws, size_t ws_size,
                              hipStream_t stream) {
  (void)in_sizes; (void)n_in; (void)out_size; (void)ws_size;
  const float* x       = (const float*)d_in[0];
  const float* conv1_w = (const float*)d_in[1];
  const float* gn1_g   = (const float*)d_in[2];
  const float* gn1_b   = (const float*)d_in[3];
  const float* conv2_w = (const float*)d_in[4];
  const float* gn2_g   = (const float*)d_in[5];
  const float* gn2_b   = (const float*)d_in[6];
  const float* proj_w  = (const float*)d_in[7];
  const float* proj_b  = (const float*)d_in[8];
  const float* A       = (const float*)d_in[9];
  const float* lin1_w  = (const float*)d_in[10];
  const float* ln1_g   = (const float*)d_in[11];
  const float* ln1_b   = (const float*)d_in[12];
  const float* lin2_w  = (const float*)d_in[13];
  const float* ln2_g   = (const float*)d_in[14];
  const float* ln2_b   = (const float*)d_in[15];
  const float* on_g    = (const float*)d_in[16];
  const float* on_b    = (const float*)d_in[17];
  float* out = (float*)d_out;

  float* wsf = (float*)d_ws;
  float* stats2 = wsf;                              // 16384 f (zeroed)
  float* hbar   = wsf + 16384;                      // 65536 f (zeroed)
  float* stats1 = wsf + 81920;                      // 16384 f
  _Float16* w2tf = (_Float16*)(wsf + 98304);        // 28672 f16
  _Float16* w1h  = (_Float16*)(wsf + 112640);       // 2048 f16
  __half* y2h    = (__half*)(wsf + 113664);         // 67108864 f16 (128 MB)

  hipMemsetAsync(stats2, 0, (16384 + 65536) * sizeof(float), stream);
  k_prep<<<120, 256, 0, stream>>>(conv2_w, conv1_w, w2tf, w1h);
  k_stats1<<<NS, 64, 0, stream>>>(x, conv1_w, stats1);
  k_conv<<<NS * 16, 256, 0, stream>>>(x, w1h, gn1_g, gn1_b, stats1, w2tf,
                                      y2h, stats2);
  k_gn2mean<<<NS * 4, 256, 0, stream>>>(y2h, stats2, gn2_g, gn2_b, hbar);
  k_head<<<256, 256, 0, stream>>>(hbar, proj_w, proj_b, A,
                                  lin1_w, ln1_g, ln1_b,
                                  lin2_w, ln2_g, ln2_b,
                                  on_g, on_b, out);
}

// Round 13
// 311.725 us; speedup vs baseline: 1.3230x; 1.3230x over previous
//
#include <hip/hip_runtime.h>
#include <hip/hip_fp16.h>
#include <math.h>

#define NS   1024
#define TIN  4096
#define T1   2048
#define T2   1024
#define TW   64
#define NG   8
#define DD   128

typedef __attribute__((ext_vector_type(8))) _Float16 f16x8;
typedef __attribute__((ext_vector_type(4))) float    f32x4;
typedef __attribute__((ext_vector_type(2))) float    f32x2;

// tanh-form gelu, exp folded to exp2 (|dev from exact| ~3e-4)
__device__ __forceinline__ float gelu_fast(float x) {
  float t = x * x;
  float p = fmaf(0.044715f, t, 1.0f);
  float u = 2.3022038f * x * p;              // 2*sqrt(2/pi)*log2(e)
  float e = exp2f(u);
  float r = __builtin_amdgcn_rcpf(e + 1.0f);
  return fmaf(-x, r, x);                      // x * e/(e+1)
}

// ------- Kernel A: conv1 stats (Gram trick) + weight prep, merged ---------
// blocks 0..NS-1: stats for n=blockIdx. blocks NS..NS+31: weight prep.
__global__ __launch_bounds__(64) void k_prep_stats(
    const float* __restrict__ x, const float* __restrict__ w1,
    const float* __restrict__ w2,
    float* __restrict__ stats1, _Float16* __restrict__ w2tf,
    _Float16* __restrict__ w1h) {
  if (blockIdx.x >= NS) {
    int base = (blockIdx.x - NS) * 64 + threadIdx.x;
    for (int i = base; i < 28672 + 2048; i += 32 * 64) {
      if (i < 28672) {
        int kk = i >> 12;
        int r = i & 4095;
        int co = r >> 6, ci = r & 63;
        w2tf[i] = (_Float16)w2[(co * 64 + ci) * 7 + kk];
      } else {
        int r = i - 28672;
        int ci = r >> 5, k = r & 31;
        w1h[r] = (k < 9) ? (_Float16)w1[ci * 9 + k] : (_Float16)0.f;
      }
    }
    return;
  }
  int n = blockIdx.x;
  __shared__ float xw[4112];
  const float* xr = x + (size_t)n * TIN;
  for (int i = threadIdx.x; i < 4112; i += 64) {
    int xi = i - 4;
    xw[i] = (xi >= 0 && xi < TIN) ? xr[xi] : 0.f;
  }
  __syncthreads();
  float C[45], S[9];
#pragma unroll
  for (int c = 0; c < 45; c++) C[c] = 0.f;
#pragma unroll
  for (int i = 0; i < 9; i++) S[i] = 0.f;
  int l = threadIdx.x;
  for (int j = 0; j < 32; j++) {
    int t = l + 64 * j;
    float w[9];
#pragma unroll
    for (int i = 0; i < 9; i++) w[i] = xw[2 * t + i];
#pragma unroll
    for (int i = 0; i < 9; i++) S[i] += w[i];
    int c = 0;
#pragma unroll
    for (int i = 0; i < 9; i++)
#pragma unroll
      for (int jj = i; jj < 9; jj++) { C[c] = fmaf(w[i], w[jj], C[c]); c++; }
  }
#pragma unroll
  for (int off = 1; off < 64; off <<= 1) {
#pragma unroll
    for (int i = 0; i < 9; i++) S[i] += __shfl_xor(S[i], off, 64);
#pragma unroll
    for (int c = 0; c < 45; c++) C[c] += __shfl_xor(C[c], off, 64);
  }
  float wv[9];
#pragma unroll
  for (int i = 0; i < 9; i++) wv[i] = w1[l * 9 + i];
  float sm = 0.f, sq = 0.f;
  {
    int c = 0;
#pragma unroll
    for (int i = 0; i < 9; i++) {
      sm = fmaf(wv[i], S[i], sm);
#pragma unroll
      for (int jj = i; jj < 9; jj++) {
        float f = (jj == i) ? wv[i] * wv[jj] : 2.f * wv[i] * wv[jj];
        sq = fmaf(f, C[c], sq); c++;
      }
    }
  }
#pragma unroll
  for (int off = 1; off < 8; off <<= 1) {
    sm += __shfl_xor(sm, off, 64);
    sq += __shfl_xor(sq, off, 64);
  }
  if ((l & 7) == 0) {
    float m = sm * (1.f / 16384.f);
    float v = sq * (1.f / 16384.f) - m * m;
    stats1[(n * NG + (l >> 3)) * 2 + 0] = m;
    stats1[(n * NG + (l >> 3)) * 2 + 1] = rsqrtf(v + 1e-5f);
  }
}

// ---------------- Kernel B: conv1(MFMA)+GN1+gelu -> conv2(MFMA) -> y2(fp8)
// R5 phase A/B verbatim (local optimum); epilogue stores fp8; 7 blocks/CU.
__global__ __launch_bounds__(256, 7) void k_conv(
    const float* __restrict__ x, const _Float16* __restrict__ w1h,
    const float* __restrict__ g1, const float* __restrict__ b1,
    const float* __restrict__ stats1, const _Float16* __restrict__ w2tf,
    unsigned char* __restrict__ y2, float* __restrict__ stats2) {
  constexpr int ROWS = 144, HS = 72;
  __shared__ __align__(16) _Float16 h1s[ROWS * HS];  // 20736 B; reused as tr8
  __shared__ _Float16 xh[320];
  __shared__ float scs[TW], bss[TW];

  const int tid = threadIdx.x;
  const int n = blockIdx.x >> 4;
  const int tile = blockIdx.x & 15;
  const int t0 = tile << 6;
  const bool chk = (tile == 0) || (tile == 15);

  const float* xr = x + (size_t)n * TIN;
  for (int i = tid; i < 320; i += 256) {
    int xi = 4 * t0 - 10 + i;
    xh[i] = (i < 278 && xi >= 0 && xi < TIN) ? (_Float16)xr[xi] : (_Float16)0.f;
  }
  if (tid < TW) {
    int ci = tid, g = ci >> 3;
    float m = stats1[(n * NG + g) * 2 + 0];
    float is = stats1[(n * NG + g) * 2 + 1];
    float s = is * g1[ci];
    scs[ci] = s;
    bss[ci] = b1[ci] - m * s;
  }
  __syncthreads();

  const int lane = tid & 63;
  const int wv = tid >> 6;
  const int m = lane & 15;
  const int q = lane >> 4;

  // ---- phase A: conv1 via f16 MFMA (K padded 9->32), GN1+gelu, store f16 --
  {
    f16x8 w1f[4];
#pragma unroll
    for (int nt = 0; nt < 4; nt++)
      w1f[nt] = *(const f16x8*)&w1h[(nt * 16 + m) * 32 + 8 * q];
    float sc4[4], bs4[4];
#pragma unroll
    for (int nt = 0; nt < 4; nt++) {
      sc4[nt] = scs[nt * 16 + m];
      bs4[nt] = bss[nt * 16 + m];
    }
    for (int mt = wv; mt < 9; mt += 4) {
      int r0 = mt * 16;
      int xi0 = 2 * (r0 + m) + 8 * q;
      uint4 uu;
      uu.x = *(const unsigned*)&xh[xi0 + 0];
      uu.y = *(const unsigned*)&xh[xi0 + 2];
      uu.z = *(const unsigned*)&xh[xi0 + 4];
      uu.w = *(const unsigned*)&xh[xi0 + 6];
      f16x8 af = __builtin_bit_cast(f16x8, uu);
      int rowb = r0 + 4 * q;
#pragma unroll
      for (int nt = 0; nt < 4; nt++) {
        f32x4 d = __builtin_amdgcn_mfma_f32_16x16x32_f16(
            af, w1f[nt], (f32x4){0.f, 0.f, 0.f, 0.f}, 0, 0, 0);
#pragma unroll
        for (int r = 0; r < 4; r++) {
          float v = gelu_fast(fmaf(d[r], sc4[nt], bs4[nt]));
          if (chk) {
            int tp = 2 * t0 - 3 + rowb + r;
            if ((unsigned)tp >= (unsigned)T1) v = 0.f;
          }
          h1s[(rowb + r) * HS + nt * 16 + m] = (_Float16)v;
        }
      }
    }
  }
  __syncthreads();

  // ---- phase B: conv2 f16 MFMA. wave = all 64 t x 16-co slice ----
  const int co0 = wv * 16 + m;
  f32x4 acc[4];
#pragma unroll
  for (int mt = 0; mt < 4; mt++) acc[mt] = (f32x4){0.f, 0.f, 0.f, 0.f};

  for (int kk = 0; kk < 7; kk++) {
    f16x8 bfr[2];
#pragma unroll
    for (int ks = 0; ks < 2; ks++)
      bfr[ks] = *(const f16x8*)&w2tf[(kk * 64 + co0) * 64 + 32 * ks + 8 * q];
#pragma unroll
    for (int mt = 0; mt < 4; mt++) {
      int tl = 2 * (mt * 16 + m) + kk;
      f16x8 a0 = *(const f16x8*)&h1s[tl * HS + 8 * q];
      f16x8 a1 = *(const f16x8*)&h1s[tl * HS + 32 + 8 * q];
      acc[mt] = __builtin_amdgcn_mfma_f32_16x16x32_f16(a0, bfr[0], acc[mt], 0, 0, 0);
      acc[mt] = __builtin_amdgcn_mfma_f32_16x16x32_f16(a1, bfr[1], acc[mt], 0, 0, 0);
    }
  }

  // ---- epilogue: GN2 stats + fp8 transpose via LDS + coalesced y2 store --
  float sum = 0.f, ssq = 0.f;
#pragma unroll
  for (int mt = 0; mt < 4; mt++)
#pragma unroll
    for (int r = 0; r < 4; r++) {
      float v = acc[mt][r];
      sum += v; ssq += v * v;
    }
  sum += __shfl_xor(sum, 1, 64);  ssq += __shfl_xor(ssq, 1, 64);
  sum += __shfl_xor(sum, 2, 64);  ssq += __shfl_xor(ssq, 2, 64);
  sum += __shfl_xor(sum, 4, 64);  ssq += __shfl_xor(ssq, 4, 64);
  sum += __shfl_xor(sum, 16, 64); ssq += __shfl_xor(ssq, 16, 64);
  sum += __shfl_xor(sum, 32, 64); ssq += __shfl_xor(ssq, 32, 64);
  if (lane == 0 || lane == 8) {
    int g = 2 * wv + (lane >> 3);
    atomicAdd(&stats2[(n * NG + g) * 2 + 0], sum);
    atomicAdd(&stats2[(n * NG + g) * 2 + 1], ssq);
  }

  __syncthreads();                      // all h1s reads done; reuse as tr8
  unsigned char* tr8 = (unsigned char*)h1s;   // [64 t][80] fp8
#pragma unroll
  for (int mt = 0; mt < 4; mt++) {
    unsigned p01 = (unsigned)__builtin_amdgcn_cvt_pk_fp8_f32(
        acc[mt][0], acc[mt][1], 0, false);
    unsigned p23 = (unsigned)__builtin_amdgcn_cvt_pk_fp8_f32(
        acc[mt][2], acc[mt][3], 0, false);
    int tb = mt * 16 + q * 4;
    tr8[(tb + 0) * 80 + co0] = (unsigned char)(p01);
    tr8[(tb + 1) * 80 + co0] = (unsigned char)(p01 >> 8);
    tr8[(tb + 2) * 80 + co0] = (unsigned char)(p23);
    tr8[(tb + 3) * 80 + co0] = (unsigned char)(p23 >> 8);
  }
  __syncthreads();
  {
    int t = tid >> 2, c16 = (tid & 3) * 16;
    uint4 v = *(const uint4*)&tr8[t * 80 + c16];
    *(uint4*)&y2[((size_t)(n * 1024) + t0 + t) * 64 + c16] = v;
  }
}

// ---------------- Kernel C: GN2 + gelu + time-sum -> hbar (atomic) --------
__global__ __launch_bounds__(256) void k_gn2mean(
    const unsigned char* __restrict__ y2, const float* __restrict__ stats2,
    const float* __restrict__ g2, const float* __restrict__ b2,
    float* __restrict__ hbar) {
  int n = blockIdx.x >> 2;
  int tq = blockIdx.x & 3;
  int coct = threadIdx.x & 7;           // co-oct == GN2 group
  int tsl = threadIdx.x >> 3;           // 32 t-slices
  int co0 = coct * 8;
  float mn = stats2[(n * NG + coct) * 2 + 0] * (1.f / 8192.f);
  float e2 = stats2[(n * NG + coct) * 2 + 1] * (1.f / 8192.f);
  float istd = rsqrtf(e2 - mn * mn + 1e-5f);
  float sca[8], sh[8];
#pragma unroll
  for (int j = 0; j < 8; j++) {
    sca[j] = istd * g2[co0 + j];
    sh[j] = b2[co0 + j] - mn * sca[j];
  }
  const unsigned char* base = y2 + (size_t)n * 65536 + tq * (256 * 64);
  uint2 raw[8];
#pragma unroll
  for (int i = 0; i < 8; i++)
    raw[i] = *(const uint2*)&base[(tsl + 32 * i) * 64 + co0];
  float a[8];
#pragma unroll
  for (int j = 0; j < 8; j++) a[j] = 0.f;
#pragma unroll
  for (int i = 0; i < 8; i++) {
    f32x2 f0 = __builtin_amdgcn_cvt_pk_f32_fp8(raw[i].x, false);
    f32x2 f1 = __builtin_amdgcn_cvt_pk_f32_fp8(raw[i].x, true);
    f32x2 f2 = __builtin_amdgcn_cvt_pk_f32_fp8(raw[i].y, false);
    f32x2 f3 = __builtin_amdgcn_cvt_pk_f32_fp8(raw[i].y, true);
    a[0] += gelu_fast(fmaf(f0.x, sca[0], sh[0]));
    a[1] += gelu_fast(fmaf(f0.y, sca[1], sh[1]));
    a[2] += gelu_fast(fmaf(f1.x, sca[2], sh[2]));
    a[3] += gelu_fast(fmaf(f1.y, sca[3], sh[3]));
    a[4] += gelu_fast(fmaf(f2.x, sca[4], sh[4]));
    a[5] += gelu_fast(fmaf(f2.y, sca[5], sh[5]));
    a[6] += gelu_fast(fmaf(f3.x, sca[6], sh[6]));
    a[7] += gelu_fast(fmaf(f3.y, sca[7], sh[7]));
  }
  __shared__ float red[32][64];
  *(float4*)&red[tsl][co0] = *(float4*)&a[0];
  *(float4*)&red[tsl][co0 + 4] = *(float4*)&a[4];
  __syncthreads();
  if (threadIdx.x < 64) {
    float s = 0.f;
#pragma unroll 8
    for (int r = 0; r < 32; r++) s += red[r][threadIdx.x];
    atomicAdd(&hbar[n * 64 + threadIdx.x], s);
  }
}

// ---------------- Kernel D: proj + GCN layers + LN + node mean ------------
__global__ __launch_bounds__(256) void k_head(
    const float* __restrict__ hbar,
    const float* __restrict__ pw, const float* __restrict__ pb,
    const float* __restrict__ A,
    const float* __restrict__ l1w, const float* __restrict__ l1g, const float* __restrict__ l1b,
    const float* __restrict__ l2w, const float* __restrict__ l2g, const float* __restrict__ l2b,
    const float* __restrict__ og, const float* __restrict__ ob,
    float* __restrict__ out) {
  int b = blockIdx.x;
  __shared__ float h4[4][TW];
  __shared__ float H[4][DD];
  __shared__ float Hm[4][DD];
  __shared__ float Xs[4][DD];
  __shared__ float At[16], Ah[16], dinv[4];
  {
    int i = threadIdx.x;
    int c = i >> 6, k = i & 63;
    h4[c][k] = hbar[(b * 4 + c) * TW + k] * (1.f / 1024.f);
  }
  if (threadIdx.x < 16)
    At[threadIdx.x] = A[threadIdx.x] + ((threadIdx.x % 5) == 0 ? 1.f : 0.f);
  __syncthreads();
  if (threadIdx.x < 4) {
    float dg = At[threadIdx.x * 4] + At[threadIdx.x * 4 + 1] +
               At[threadIdx.x * 4 + 2] + At[threadIdx.x * 4 + 3];
    dinv[threadIdx.x] = rsqrtf(dg + 1e-6f);
  }
  for (int idx = threadIdx.x; idx < 512; idx += 256) {
    int c = idx >> 7, d = idx & 127;
    float acc = pb[d];
    const float* wrow = pw + d * TW;
#pragma unroll 8
    for (int k = 0; k < TW; k++) acc += h4[c][k] * wrow[k];
    H[c][d] = acc;
  }
  __syncthreads();
  if (threadIdx.x < 16)
    Ah[threadIdx.x] = dinv[threadIdx.x >> 2] * At[threadIdx.x] * dinv[threadIdx.x & 3];
  __syncthreads();
  for (int L = 0; L < 2; L++) {
    const float* lw = L ? l2w : l1w;
    const float* lg = L ? l2g : l1g;
    const float* lb = L ? l2b : l1b;
    for (int idx = threadIdx.x; idx < 512; idx += 256) {
      int nn = idx >> 7, d = idx & 127;
      Hm[nn][d] = Ah[nn * 4 + 0] * H[0][d] + Ah[nn * 4 + 1] * H[1][d] +
                  Ah[nn * 4 + 2] * H[2][d] + Ah[nn * 4 + 3] * H[3][d];
    }
    __syncthreads();
    for (int idx = threadIdx.x; idx < 512; idx += 256) {
      int nn = idx >> 7, d = idx & 127;
      float acc = 0.f;
      const float* wrow = lw + d * DD;
#pragma unroll 8
      for (int k = 0; k < DD; k++) acc += Hm[nn][k] * wrow[k];
      Xs[nn][d] = acc;
    }
    __syncthreads();
    {
      int w = threadIdx.x >> 6, lane = threadIdx.x & 63;
      float v0 = Xs[w][lane], v1 = Xs[w][lane + 64];
      float s = v0 + v1, qq = v0 * v0 + v1 * v1;
#pragma unroll
      for (int off = 1; off < 64; off <<= 1) {
        s += __shfl_xor(s, off, 64);
        qq += __shfl_xor(qq, off, 64);
      }
      float mm = s * (1.f / 128.f);
      float istd = rsqrtf(qq * (1.f / 128.f) - mm * mm + 1e-5f);
      H[w][lane]      = gelu_fast((v0 - mm) * istd * lg[lane] + lb[lane]);
      H[w][lane + 64] = gelu_fast((v1 - mm) * istd * lg[lane + 64] + lb[lane + 64]);
    }
    __syncthreads();
  }
  {
    int w = threadIdx.x >> 6, lane = threadIdx.x & 63;
    float v0 = H[w][lane], v1 = H[w][lane + 64];
    float s = v0 + v1, qq = v0 * v0 + v1 * v1;
#pragma unroll
    for (int off = 1; off < 64; off <<= 1) {
      s += __shfl_xor(s, off, 64);
      qq += __shfl_xor(qq, off, 64);
    }
    float mm = s * (1.f / 128.f);
    float istd = rsqrtf(qq * (1.f / 128.f) - mm * mm + 1e-5f);
    Xs[w][lane]      = (v0 - mm) * istd * og[lane] + ob[lane];
    Xs[w][lane + 64] = (v1 - mm) * istd * og[lane + 64] + ob[lane + 64];
  }
  __syncthreads();
  if (threadIdx.x < DD) {
    int d = threadIdx.x;
    out[b * DD + d] = 0.25f * (Xs[0][d] + Xs[1][d] + Xs[2][d] + Xs[3][d]);
  }
}

extern "C" void kernel_launch(void* const* d_in, const int* in_sizes, int n_in,
                              void* d_out, int out_size, void* d_ws, size_t ws_size,
                              hipStream_t stream) {
  (void)in_sizes; (void)n_in; (void)out_size; (void)ws_size;
  const float* x       = (const float*)d_in[0];
  const float* conv1_w = (const float*)d_in[1];
  const float* gn1_g   = (const float*)d_in[2];
  const float* gn1_b   = (const float*)d_in[3];
  const float* conv2_w = (const float*)d_in[4];
  const float* gn2_g   = (const float*)d_in[5];
  const float* gn2_b   = (const float*)d_in[6];
  const float* proj_w  = (const float*)d_in[7];
  const float* proj_b  = (const float*)d_in[8];
  const float* A       = (const float*)d_in[9];
  const float* lin1_w  = (const float*)d_in[10];
  const float* ln1_g   = (const float*)d_in[11];
  const float* ln1_b   = (const float*)d_in[12];
  const float* lin2_w  = (const float*)d_in[13];
  const float* ln2_g   = (const float*)d_in[14];
  const float* ln2_b   = (const float*)d_in[15];
  const float* on_g    = (const float*)d_in[16];
  const float* on_b    = (const float*)d_in[17];
  float* out = (float*)d_out;

  float* wsf = (float*)d_ws;
  float* stats2 = wsf;                              // 16384 f (zeroed)
  float* hbar   = wsf + 16384;                      // 65536 f (zeroed)
  float* stats1 = wsf + 81920;                      // 16384 f
  _Float16* w2tf = (_Float16*)(wsf + 98304);        // 28672 f16
  _Float16* w1h  = (_Float16*)(wsf + 112640);       // 2048 f16
  unsigned char* y2 = (unsigned char*)(wsf + 113664); // 67108864 B fp8 (64 MB)

  hipMemsetAsync(stats2, 0, (16384 + 65536) * sizeof(float), stream);
  k_prep_stats<<<NS + 32, 64, 0, stream>>>(x, conv1_w, conv2_w,
                                           stats1, w2tf, w1h);
  k_conv<<<NS * 16, 256, 0, stream>>>(x, w1h, gn1_g, gn1_b, stats1, w2tf,
                                      y2, stats2);
  k_gn2mean<<<NS * 4, 256, 0, stream>>>(y2, stats2, gn2_g, gn2_b, hbar);
  k_head<<<256, 256, 0, stream>>>(hbar, proj_w, proj_b, A,
                                  lin1_w, ln1_g, ln1_b,
                                  lin2_w, ln2_g, ln2_b,
                                  on_g, on_b, out);
}